// Round 10
// baseline (173.459 us; speedup 1.0000x reference)
//
#include <hip/hip_runtime.h>
#include <cmath>

typedef float floatx4 __attribute__((ext_vector_type(4)));
typedef __bf16 bf16x8 __attribute__((ext_vector_type(8)));

#define NDT 512
#define NELF 262144.0f

// ---- ws layout ----
// ctl (uint idx): FLAG [(rg*8+cb)*8] stride 8, 2048 uints; RCNT at 4096 + sa*32.
// floats: PART1 ws+8192 (sa*256+rg*8+cb); PART2 ws+16384 ((sa*32+rg)*32).
// data (float offsets):
#define AF0_OFF 65536
#define AF1_OFF (65536 + 262144)
#define YF_OFF (65536 + 2 * 262144)

#define RTOLc 1e-3f
#define ATOLc 1e-6f
#define TAc 1.0f
#define TBc 1.0f
#define TCc 0.0f

union UB { uint4 u; bf16x8 v; };
union UB2 { unsigned long long q[2]; uint4 u; bf16x8 v; };

__device__ __forceinline__ uint32_t f2bf(float f) {
  uint32_t u = __float_as_uint(f);
  return (u + 0x7fffu + ((u >> 16) & 1u)) >> 16;
}

#define AST(p, v) __hip_atomic_store((p), (v), __ATOMIC_RELAXED, __HIP_MEMORY_SCOPE_AGENT)
#define ALD(p) __hip_atomic_load((p), __ATOMIC_RELAXED, __HIP_MEMORY_SCOPE_AGENT)

// ---- tiny ctl zeroing (FLAG + RCNT; ws is 0xAA-poisoned before every launch) ----
__global__ __launch_bounds__(256) void ctl_zero(unsigned* __restrict__ ctl) {
  for (int i = threadIdx.x; i < 8192; i += 256) ctl[i] = 0u;
}

// ---- fused kernel: pack-from-source + A0 GEMM + RK45 + out GEMM ----
// Plain launch (no cg API); co-residency by capacity: grid=256=CU count,
// launch_bounds(256,1), 34 KB LDS -> >=2 blocks/CU worth of resources.
__global__ __launch_bounds__(256, 1) void ode_mfma(const float* __restrict__ x,
                                                   const float* __restrict__ C,
                                                   const float* __restrict__ P,
                                                   const float* __restrict__ F,
                                                   float* __restrict__ out,
                                                   float* __restrict__ ws) {
  __shared__ __align__(16) float red[4][16][68];
  __shared__ __align__(16) unsigned short ldsX[16 * 64 * 8];  // 16 KiB
  __shared__ float bred[4];
  __shared__ float shb0s, shb1s;

  unsigned* FLAG = (unsigned*)ws;               // per-block phase flag, stride 8
  unsigned* RCNT = ((unsigned*)ws) + 4096;      // per-slot release counters, stride 32
  float* PART1 = ws + 8192;
  float* PART2 = ws + 16384;
  unsigned long long* AfA = (unsigned long long*)(ws + AF0_OFF);
  unsigned long long* AfB = (unsigned long long*)(ws + AF1_OFF);
  unsigned long long* YF = (unsigned long long*)(ws + YF_OFF);

  const int tid = threadIdx.x;
  const int lane = tid & 63;
  const int w = tid >> 6;          // wave id = K-chunk
  const int cb = blockIdx.x >> 5;  // col-slice 64*cb..64*cb+63
  const int rg = blockIdx.x & 31;  // rows 16*rg..16*rg+15
  const int rl = tid & 15;         // owned row
  const int gcq = cb * 16 + (tid >> 4);  // owned global col-quad

  // B-frag lane mapping: n = nbase + cf*16, K = kc*32 + kq8 + j
  const int nbase = cb * 64 + (lane & 15);
  const int kq8 = ((lane >> 4) & 3) * 8;

  // persistent register-resident C-frags (K=1024), packed directly from C.
  // Ct[K][n] == C[n*1024 + K]; frag(cf, kc=8w+i), elements j=0..7 contiguous in K.
  UB Breg[4][8];
#pragma unroll
  for (int cf = 0; cf < 4; ++cf)
#pragma unroll
    for (int i = 0; i < 8; ++i) {
      const float* cp = C + (size_t)(nbase + cf * 16) * 1024 + (8 * w + i) * 32 + kq8;
      floatx4 v0 = *(const floatx4*)cp;
      floatx4 v1 = *(const floatx4*)(cp + 4);
      Breg[cf][i].u =
          make_uint4(f2bf(v0[0]) | (f2bf(v0[1]) << 16), f2bf(v0[2]) | (f2bf(v0[3]) << 16),
                     f2bf(v1[0]) | (f2bf(v1[1]) << 16), f2bf(v1[2]) | (f2bf(v1[3]) << 16));
    }

  int rg_phase = 0, par = 0;

  // arrive: 1 store to own padded flag; wait: 8 lanes poll 8 partner flags in parallel
  auto rg_barrier = [&]() {
    __syncthreads();  // compiler emits s_waitcnt vmcnt(0) before s_barrier -> stores drained
    ++rg_phase;
    if (tid == 0) AST(&FLAG[(rg * 8 + cb) * 8], (unsigned)rg_phase);
    if (tid < 8) {
      while (ALD(&FLAG[(rg * 8 + tid) * 8]) < (unsigned)rg_phase) __builtin_amdgcn_s_sleep(1);
    }
    __syncthreads();
  };

  // cross-wave K-reduction of 4 col-frag accumulators -> thread's floatx4 patch
  auto reduce4 = [&](floatx4 a0, floatx4 a1, floatx4 a2, floatx4 a3) -> floatx4 {
    __syncthreads();  // guard red reuse
    const int q = lane >> 4, l4 = lane & 15;
#pragma unroll
    for (int ri = 0; ri < 4; ++ri) {
      red[w][4 * q + ri][l4] = a0[ri];
      red[w][4 * q + ri][16 + l4] = a1[ri];
      red[w][4 * q + ri][32 + l4] = a2[ri];
      red[w][4 * q + ri][48 + l4] = a3[ri];
    }
    __syncthreads();
    const int c0 = (tid >> 4) * 4;
    floatx4 o = *(const floatx4*)&red[0][rl][c0];
    o += *(const floatx4*)&red[1][rl][c0];
    o += *(const floatx4*)&red[2][rl][c0];
    o += *(const floatx4*)&red[3][rl][c0];
    return o;
  };

  // basis write slot (K=1024 frag layout, sin/cos interleaved over K=2*col)
  const int kcw = gcq >> 2;
  const int alw = rl | ((gcq & 3) << 4);
  const size_t wslot = ((size_t)(rg * 32 + kcw) * 64 + alw) * 2;

  auto write_basis = [&](floatx4 av, float targ) {
    uint32_t d[4];
#pragma unroll
    for (int e = 0; e < 4; ++e) {
      float s, c;
      __sincosf(TAc * av[e] + targ, &s, &c);
      d[e] = f2bf(s) | (f2bf(c) << 16);
    }
    unsigned long long* Ap = (par ? AfB : AfA) + wslot;
    AST(Ap, (unsigned long long)d[0] | ((unsigned long long)d[1] << 32));
    AST(Ap + 1, (unsigned long long)d[2] | ((unsigned long long)d[3] << 32));
  };

  auto gemm = [&]() -> floatx4 {
    const unsigned long long* Ap =
        (par ? AfB : AfA) + ((size_t)(rg * 32 + 8 * w) * 64 + lane) * 2;
    UB2 a[8];
#pragma unroll
    for (int i = 0; i < 8; ++i) {
      a[i].q[0] = ALD(Ap + (size_t)i * 128);
      a[i].q[1] = ALD(Ap + (size_t)i * 128 + 1);
    }
    floatx4 acc0 = {0.f, 0.f, 0.f, 0.f}, acc1 = acc0, acc2 = acc0, acc3 = acc0;
#pragma unroll
    for (int i = 0; i < 8; ++i) {
      acc0 = __builtin_amdgcn_mfma_f32_16x16x32_bf16(a[i].v, Breg[0][i].v, acc0, 0, 0, 0);
      acc1 = __builtin_amdgcn_mfma_f32_16x16x32_bf16(a[i].v, Breg[1][i].v, acc1, 0, 0, 0);
      acc2 = __builtin_amdgcn_mfma_f32_16x16x32_bf16(a[i].v, Breg[2][i].v, acc2, 0, 0, 0);
      acc3 = __builtin_amdgcn_mfma_f32_16x16x32_bf16(a[i].v, Breg[3][i].v, acc3, 0, 0, 0);
    }
    par ^= 1;
    return reduce4(acc0, acc1, acc2, acc3);
  };

  auto block_sum = [&](float v) -> float {
#pragma unroll
    for (int o = 32; o; o >>= 1) v += __shfl_down(v, o, 64);
    __syncthreads();
    if (lane == 0) bred[w] = v;
    __syncthreads();
    return (tid == 0) ? (bred[0] + bred[1] + bred[2] + bred[3]) : 0.0f;
  };

  // deterministic 2-level grid reduce (flag arrival + zeroed RCNT release)
  auto grid_reduce = [&](float va, float vb, int sa, int sb, bool two) -> float2 {
    float ba = block_sum(va);
    float bb = two ? block_sum(vb) : 0.0f;
    ++rg_phase;
    if (tid == 0) {
      AST(&PART1[sa * 256 + rg * 8 + cb], ba);
      if (two) AST(&PART1[sb * 256 + rg * 8 + cb], bb);
      asm volatile("s_waitcnt vmcnt(0)" ::: "memory");
      AST(&FLAG[(rg * 8 + cb) * 8], (unsigned)rg_phase);
    }
    if (cb == 0 && tid < 8) {
      while (ALD(&FLAG[(rg * 8 + tid) * 8]) < (unsigned)rg_phase) __builtin_amdgcn_s_sleep(1);
    }
    __syncthreads();
    if (cb == 0 && tid == 0) {
      float ra = 0.f, rb = 0.f;
#pragma unroll
      for (int i = 0; i < 8; ++i) ra += ALD(&PART1[sa * 256 + rg * 8 + i]);
      AST(&PART2[(size_t)(sa * 32 + rg) * 32], ra);
      if (two) {
#pragma unroll
        for (int i = 0; i < 8; ++i) rb += ALD(&PART1[sb * 256 + rg * 8 + i]);
        AST(&PART2[(size_t)(sb * 32 + rg) * 32], rb);
      }
      asm volatile("s_waitcnt vmcnt(0)" ::: "memory");
      __hip_atomic_fetch_add(&RCNT[sa * 32], 1u, __ATOMIC_RELAXED, __HIP_MEMORY_SCOPE_AGENT);
    }
    if (tid == 0) {
      while (ALD(&RCNT[sa * 32]) < 32u) __builtin_amdgcn_s_sleep(1);
    }
    __syncthreads();
    if (w == 0) {
      float x0 = (lane < 32) ? ALD(&PART2[(size_t)(sa * 32 + lane) * 32]) : 0.0f;
      float x1 = (two && lane < 32) ? ALD(&PART2[(size_t)(sb * 32 + lane) * 32]) : 0.0f;
#pragma unroll
      for (int o = 16; o; o >>= 1) {
        x0 += __shfl_down(x0, o, 32);
        x1 += __shfl_down(x1, o, 32);
      }
      if (lane == 0) { shb0s = x0; shb1s = x1; }
    }
    __syncthreads();
    return make_float2(shb0s, shb1s);
  };

  // K=512 B-frag built inline from row-major M[K][N] (P or F)
  auto load_b512 = [&](const float* M, int Kb, int cf) -> UB {
    const float* pp = M + (size_t)Kb * NDT + nbase + cf * 16;
    uint32_t e0 = f2bf(pp[0]);
    uint32_t e1 = f2bf(pp[512]);
    uint32_t e2 = f2bf(pp[1024]);
    uint32_t e3 = f2bf(pp[1536]);
    uint32_t e4 = f2bf(pp[2048]);
    uint32_t e5 = f2bf(pp[2560]);
    uint32_t e6 = f2bf(pp[3072]);
    uint32_t e7 = f2bf(pp[3584]);
    UB b;
    b.u = make_uint4(e0 | (e1 << 16), e2 | (e3 << 16), e4 | (e5 << 16), e6 | (e7 << 16));
    return b;
  };

  // ---- phase A0: y = (x @ P) patch, K=512 MFMA, P-frags built inline ----
  floatx4 y, fy, k2, k3, k4, k5, k6, k7, yn, av;
  {
    for (int idx = tid; idx < 8192; idx += 256) {
      int r = idx >> 9, k = idx & 511;
      float v = x[(size_t)(rg * 16 + r) * NDT + k];
      int al = r | (((k >> 3) & 3) << 4);
      ldsX[((size_t)(k >> 5) * 64 + al) * 8 + (k & 7)] = (unsigned short)f2bf(v);
    }
    __syncthreads();
    floatx4 a0 = {0.f, 0.f, 0.f, 0.f}, a1 = a0, a2 = a0, a3 = a0;
#pragma unroll
    for (int i = 0; i < 4; ++i) {
      UB a;
      a.u = *(const uint4*)(ldsX + ((size_t)(4 * w + i) * 64 + lane) * 8);
      const int Kb = (4 * w + i) * 32 + kq8;
      a0 = __builtin_amdgcn_mfma_f32_16x16x32_bf16(a.v, load_b512(P, Kb, 0).v, a0, 0, 0, 0);
      a1 = __builtin_amdgcn_mfma_f32_16x16x32_bf16(a.v, load_b512(P, Kb, 1).v, a1, 0, 0, 0);
      a2 = __builtin_amdgcn_mfma_f32_16x16x32_bf16(a.v, load_b512(P, Kb, 2).v, a2, 0, 0, 0);
      a3 = __builtin_amdgcn_mfma_f32_16x16x32_bf16(a.v, load_b512(P, Kb, 3).v, a3, 0, 0, 0);
    }
    y = reduce4(a0, a1, a2, a3);
  }

  // ---- initial step selection (scipy _select_initial_step) ----
  write_basis(y, TCc + TBc * 0.0f);
  rg_barrier();
  fy = gemm();  // f0
  {
    float s0 = 0.f, s1 = 0.f;
#pragma unroll
    for (int r = 0; r < 4; ++r) {
      float sv = ATOLc + RTOLc * fabsf(y[r]);
      float a = y[r] / sv, b = fy[r] / sv;
      s0 += a * a;
      s1 += b * b;
    }
    float2 d01 = grid_reduce(s0, s1, 0, 1, true);
    const float d0 = sqrtf(d01.x / NELF);
    const float d1 = sqrtf(d01.y / NELF);
    const float h0 = (d0 < 1e-5f || d1 < 1e-5f) ? 1e-6f : 0.01f * d0 / d1;
    av = y + h0 * fy;
    write_basis(av, TCc + TBc * h0);
    rg_barrier();
    k2 = gemm();  // f1 (temp)
    float s2 = 0.f;
#pragma unroll
    for (int r = 0; r < 4; ++r) {
      float sv = ATOLc + RTOLc * fabsf(y[r]);
      float dd = (k2[r] - fy[r]) / sv;
      s2 += dd * dd;
    }
    const float d2 = sqrtf(grid_reduce(s2, 0.f, 2, 0, false).x / NELF) / h0;
    const float dmax = fmaxf(d1, d2);
    const float h1i = (dmax <= 1e-15f) ? fmaxf(1e-6f, h0 * 1e-3f) : powf(0.01f / dmax, 0.2f);
    float h = fminf(fminf(100.0f * h0, h1i), 1.0f);
    float t = 0.0f;
    bool done = false;
    int it = 0;

    const float a21 = (float)(1.0 / 5.0);
    const float a31 = (float)(3.0 / 40.0), a32 = (float)(9.0 / 40.0);
    const float a41 = (float)(44.0 / 45.0), a42 = (float)(-56.0 / 15.0), a43 = (float)(32.0 / 9.0);
    const float a51 = (float)(19372.0 / 6561.0), a52 = (float)(-25360.0 / 2187.0),
                a53 = (float)(64448.0 / 6561.0), a54 = (float)(-212.0 / 729.0);
    const float a61 = (float)(9017.0 / 3168.0), a62 = (float)(-355.0 / 33.0),
                a63 = (float)(46732.0 / 5247.0), a64 = (float)(49.0 / 176.0),
                a65 = (float)(-5103.0 / 18656.0);
    const float b1 = (float)(35.0 / 384.0), b3 = (float)(500.0 / 1113.0),
                b4 = (float)(125.0 / 192.0), b5 = (float)(-2187.0 / 6784.0),
                b6 = (float)(11.0 / 84.0);
    const float e1c = (float)(71.0 / 57600.0), e3c = (float)(-71.0 / 16695.0),
                e4c = (float)(71.0 / 1920.0), e5c = (float)(-17253.0 / 339200.0),
                e6c = (float)(22.0 / 525.0), e7c = (float)(-1.0 / 40.0);
    const float c89 = (float)(8.0 / 9.0);

    while (true) {
      const float hs = fminf(h, 1.0f - t);

      av = y + (hs * a21) * fy;
      write_basis(av, TCc + TBc * (t + 0.2f * hs));
      rg_barrier();
      k2 = gemm();

      av = y + hs * (a31 * fy + a32 * k2);
      write_basis(av, TCc + TBc * (t + 0.3f * hs));
      rg_barrier();
      k3 = gemm();

      av = y + hs * (a41 * fy + a42 * k2 + a43 * k3);
      write_basis(av, TCc + TBc * (t + 0.8f * hs));
      rg_barrier();
      k4 = gemm();

      av = y + hs * (a51 * fy + a52 * k2 + a53 * k3 + a54 * k4);
      write_basis(av, TCc + TBc * (t + c89 * hs));
      rg_barrier();
      k5 = gemm();

      av = y + hs * (a61 * fy + a62 * k2 + a63 * k3 + a64 * k4 + a65 * k5);
      write_basis(av, TCc + TBc * (t + hs));
      rg_barrier();
      k6 = gemm();

      yn = y + hs * (b1 * fy + b3 * k3 + b4 * k4 + b5 * k5 + b6 * k6);
      write_basis(yn, TCc + TBc * (t + hs));  // FSAL stage input
      rg_barrier();
      k7 = gemm();

      float es = 0.f;
#pragma unroll
      for (int r = 0; r < 4; ++r) {
        float errc = hs * (e1c * fy[r] + e3c * k3[r] + e4c * k4[r] + e5c * k5[r] + e6c * k6[r] +
                           e7c * k7[r]);
        float sv = ATOLc + RTOLc * fmaxf(fabsf(y[r]), fabsf(yn[r]));
        float dd = errc / sv;
        es += dd * dd;
      }
      const float en = sqrtf(grid_reduce(es, 0.f, 3 + it, 0, false).x / NELF);
      const bool accept = en < 1.0f;
      const float safe = fmaxf(en, 1e-10f);
      float fac = 0.9f * powf(safe, -0.2f);
      fac = accept ? fminf(10.0f, fac) : fmaxf(0.2f, fac);
      if (accept) {
        t = t + hs;
        y = yn;
        fy = k7;
      }
      h = hs * fac;
      done = done || (t >= 1.0f - 1e-7f);
      ++it;
      if (done || it >= 20) break;
    }
  }

  // ---- final phase: out = A_f @ F (exchange y as K=512 frags, F-frags inline) ----
  {
    uint32_t d0 = f2bf(y[0]) | (f2bf(y[1]) << 16);
    uint32_t d1 = f2bf(y[2]) | (f2bf(y[3]) << 16);
    const int kcF = gcq >> 3;
    const int alF = rl | (((gcq >> 1) & 3) << 4);
    AST(YF + ((size_t)(rg * 16 + kcF) * 64 + alF) * 2 + (gcq & 1),
        (unsigned long long)d0 | ((unsigned long long)d1 << 32));
  }
  rg_barrier();
  {
    floatx4 a0 = {0.f, 0.f, 0.f, 0.f}, a1 = a0, a2 = a0, a3 = a0;
#pragma unroll
    for (int i = 0; i < 4; ++i) {
      UB2 a;
      const size_t base = ((size_t)(rg * 16 + 4 * w + i) * 64 + lane) * 2;
      a.q[0] = ALD(YF + base);
      a.q[1] = ALD(YF + base + 1);
      const int Kb = (4 * w + i) * 32 + kq8;
      a0 = __builtin_amdgcn_mfma_f32_16x16x32_bf16(a.v, load_b512(F, Kb, 0).v, a0, 0, 0, 0);
      a1 = __builtin_amdgcn_mfma_f32_16x16x32_bf16(a.v, load_b512(F, Kb, 1).v, a1, 0, 0, 0);
      a2 = __builtin_amdgcn_mfma_f32_16x16x32_bf16(a.v, load_b512(F, Kb, 2).v, a2, 0, 0, 0);
      a3 = __builtin_amdgcn_mfma_f32_16x16x32_bf16(a.v, load_b512(F, Kb, 3).v, a3, 0, 0, 0);
    }
    floatx4 o = reduce4(a0, a1, a2, a3);
    *(floatx4*)(out + (size_t)(rg * 16 + rl) * NDT + cb * 64 + (tid >> 4) * 4) = o;
  }
}

extern "C" void kernel_launch(void* const* d_in, const int* in_sizes, int n_in,
                              void* d_out, int out_size, void* d_ws, size_t ws_size,
                              hipStream_t stream) {
  (void)in_sizes; (void)n_in; (void)out_size; (void)ws_size;
  const float* x = (const float*)d_in[0];
  const float* P = (const float*)d_in[1];
  const float* C = (const float*)d_in[2];
  const float* F = (const float*)d_in[3];
  float* out = (float*)d_out;
  float* ws = (float*)d_ws;

  // zero sync flags/counters (ws is 0xAA-poisoned before every launch)
  hipLaunchKernelGGL(ctl_zero, dim3(1), dim3(256), 0, stream, (unsigned*)ws);
  // fused kernel: in-kernel operand packing + A0 + RK45 + out
  hipLaunchKernelGGL(ode_mfma, dim3(256), dim3(256), 0, stream, x, C, P, F, out, ws);
}

// Round 11
// 142.581 us; speedup vs baseline: 1.2166x; 1.2166x over previous
//
#include <hip/hip_runtime.h>
#include <cmath>

typedef float floatx4 __attribute__((ext_vector_type(4)));
typedef __bf16 bf16x8 __attribute__((ext_vector_type(8)));

#define NDT 512
#define NELF 262144.0f

// ---- ws layout (float idx) ----
// FLAG  uint [0..2048) at (rg*8+cb)*8 (padded lines)
// PART1 float [4096..10240) at sa*256 + (rg*8+cb)
// AF0 16384, AF1 16384+262144 (basis parity buffers, bf16 1 MiB each)
// YF reuses AF0 region after the final grid-wide reduce.
#define AF0_OFF 16384
#define AF1_OFF (16384 + 262144)
#define BFC_OFF (16384 + 2 * 262144)
#define BFP_OFF (BFC_OFF + 262144)
#define BFF_OFF (BFP_OFF + 131072)

#define RTOLc 1e-3f
#define ATOLc 1e-6f
#define TAc 1.0f
#define TBc 1.0f
#define TCc 0.0f

union UB { uint4 u; bf16x8 v; };
union UB2 { unsigned long long q[2]; uint4 u; bf16x8 v; };

__device__ __forceinline__ uint32_t f2bf(float f) {
  uint32_t u = __float_as_uint(f);
  return (u + 0x7fffu + ((u >> 16) & 1u)) >> 16;
}

#define AST(p, v) __hip_atomic_store((p), (v), __ATOMIC_RELAXED, __HIP_MEMORY_SCOPE_AGENT)
#define ALD(p) __hip_atomic_load((p), __ATOMIC_RELAXED, __HIP_MEMORY_SCOPE_AGENT)

// ---- pack: C (coalesced-read/scatter-write, proven) + P/F gather-style; zero ctl ----
__global__ __launch_bounds__(256) void pack_all(const float* __restrict__ C,
                                                const float* __restrict__ P,
                                                const float* __restrict__ F,
                                                __bf16* __restrict__ BfC,
                                                unsigned* __restrict__ BfP,
                                                unsigned* __restrict__ BfF,
                                                unsigned* __restrict__ ctl) {
  const int bid = blockIdx.x, tid = threadIdx.x;
  if (bid == 0) {
    for (int i = tid; i < 4096; i += 256) ctl[i] = 0u;
  }
  if (bid < 512) {
    int t = bid * 256 + tid;
    int i = t >> 8;
    int pr = t & 255;  // K0 = pr*4
    floatx4 v = *(const floatx4*)(C + (size_t)i * 1024 + pr * 4);
    uint32_t w0 = f2bf(v[0]) | (f2bf(v[1]) << 16);
    uint32_t w1 = f2bf(v[2]) | (f2bf(v[3]) << 16);
    int c0 = i >> 4;
    int kc = pr >> 3;
    int lq = (pr >> 1) & 3;
    int ln = (i & 15) | (lq << 4);
    int jp = (pr & 1) * 4;
    uint2 val; val.x = w0; val.y = w1;
    *(uint2*)(BfC + ((size_t)(c0 * 32 + kc) * 64 + ln) * 8 + jp) = val;
  } else {
    // gather-style: one thread builds one 16-B frag line (8 bf16 along K)
    const float* M = (bid < 640) ? P : F;
    unsigned* Bf = (bid < 640) ? BfP : BfF;
    int t = ((bid < 640) ? (bid - 512) : (bid - 640)) * 256 + tid;  // 0..32767
    int lane = t & 63;
    int kc = (t >> 6) & 15;
    int nf = t >> 10;
    int n = nf * 16 + (lane & 15);
    int K0 = kc * 32 + ((lane >> 4) & 3) * 8;
    const float* mp = M + (size_t)K0 * NDT + n;
    uint32_t e0 = f2bf(mp[0]);
    uint32_t e1 = f2bf(mp[512]);
    uint32_t e2 = f2bf(mp[1024]);
    uint32_t e3 = f2bf(mp[1536]);
    uint32_t e4 = f2bf(mp[2048]);
    uint32_t e5 = f2bf(mp[2560]);
    uint32_t e6 = f2bf(mp[3072]);
    uint32_t e7 = f2bf(mp[3584]);
    *(uint4*)(Bf + ((size_t)(nf * 16 + kc) * 64 + lane) * 4) =
        make_uint4(e0 | (e1 << 16), e2 | (e3 << 16), e4 | (e5 << 16), e6 | (e7 << 16));
  }
}

// ---- fused kernel: A0 GEMM + RK45 + out GEMM; plain launch, co-residency by
// capacity (grid=256=CU count, launch_bounds(256,1), 34 KB LDS). ----
__global__ __launch_bounds__(256, 1) void ode_mfma(const float* __restrict__ x,
                                                   float* __restrict__ out,
                                                   float* __restrict__ ws) {
  __shared__ __align__(16) float red[4][16][68];
  __shared__ __align__(16) unsigned short ldsX[16 * 64 * 8];  // 16 KiB
  __shared__ float bred[4];
  __shared__ float shb0s, shb1s;

  unsigned* FLAG = (unsigned*)ws;               // per-block phase flag, stride 8
  float* PART1 = ws + 4096;                     // sa*256 + blk
  unsigned long long* AfA = (unsigned long long*)(ws + AF0_OFF);
  unsigned long long* AfB = (unsigned long long*)(ws + AF1_OFF);
  unsigned long long* YF = (unsigned long long*)(ws + AF0_OFF);  // reused post-loop
  const __bf16* Bf = (const __bf16*)(ws + BFC_OFF);
  const __bf16* BfP = (const __bf16*)(ws + BFP_OFF);
  const __bf16* BfF = (const __bf16*)(ws + BFF_OFF);

  const int tid = threadIdx.x;
  const int lane = tid & 63;
  const int w = tid >> 6;          // wave id = K-chunk
  const int cb = blockIdx.x >> 5;  // col-slice 64*cb..64*cb+63
  const int rg = blockIdx.x & 31;  // rows 16*rg..16*rg+15
  const int rl = tid & 15;         // owned row
  const int gcq = cb * 16 + (tid >> 4);  // owned global col-quad
  const int blk = rg * 8 + cb;     // flag slot id

  // persistent register-resident C-frags (K=1024): wave w owns kc 8w..8w+7
  UB Breg[4][8];
#pragma unroll
  for (int cf = 0; cf < 4; ++cf)
#pragma unroll
    for (int i = 0; i < 8; ++i)
      Breg[cf][i].u =
          *(const uint4*)(Bf + (((size_t)(cb * 4 + cf) * 32 + 8 * w + i) * 64 + lane) * 8);

  int rg_phase = 0, par = 0;

  // arrive: 1 flag store; wait: 8 lanes poll the 8 same-rg flags in parallel
  auto rg_barrier = [&]() {
    __syncthreads();  // compiler emits s_waitcnt vmcnt(0) before s_barrier
    ++rg_phase;
    if (tid == 0) AST(&FLAG[blk * 8], (unsigned)rg_phase);
    if (tid < 8) {
      while (ALD(&FLAG[(rg * 8 + tid) * 8]) < (unsigned)rg_phase) __builtin_amdgcn_s_sleep(1);
    }
    __syncthreads();
  };

  // cross-wave K-reduction of 4 col-frag accumulators -> thread's floatx4 patch
  auto reduce4 = [&](floatx4 a0, floatx4 a1, floatx4 a2, floatx4 a3) -> floatx4 {
    __syncthreads();  // guard red reuse
    const int q = lane >> 4, l4 = lane & 15;
#pragma unroll
    for (int ri = 0; ri < 4; ++ri) {
      red[w][4 * q + ri][l4] = a0[ri];
      red[w][4 * q + ri][16 + l4] = a1[ri];
      red[w][4 * q + ri][32 + l4] = a2[ri];
      red[w][4 * q + ri][48 + l4] = a3[ri];
    }
    __syncthreads();
    const int c0 = (tid >> 4) * 4;
    floatx4 o = *(const floatx4*)&red[0][rl][c0];
    o += *(const floatx4*)&red[1][rl][c0];
    o += *(const floatx4*)&red[2][rl][c0];
    o += *(const floatx4*)&red[3][rl][c0];
    return o;
  };

  // basis write slot (K=1024 frag layout, sin/cos interleaved over K=2*col)
  const int kcw = gcq >> 2;
  const int alw = rl | ((gcq & 3) << 4);
  const size_t wslot = ((size_t)(rg * 32 + kcw) * 64 + alw) * 2;

  auto write_basis = [&](floatx4 av, float targ) {
    uint32_t d[4];
#pragma unroll
    for (int e = 0; e < 4; ++e) {
      float s, c;
      __sincosf(TAc * av[e] + targ, &s, &c);
      d[e] = f2bf(s) | (f2bf(c) << 16);
    }
    unsigned long long* Ap = (par ? AfB : AfA) + wslot;
    AST(Ap, (unsigned long long)d[0] | ((unsigned long long)d[1] << 32));
    AST(Ap + 1, (unsigned long long)d[2] | ((unsigned long long)d[3] << 32));
  };

  auto gemm = [&]() -> floatx4 {
    const unsigned long long* Ap =
        (par ? AfB : AfA) + ((size_t)(rg * 32 + 8 * w) * 64 + lane) * 2;
    UB2 a[8];
#pragma unroll
    for (int i = 0; i < 8; ++i) {
      a[i].q[0] = ALD(Ap + (size_t)i * 128);
      a[i].q[1] = ALD(Ap + (size_t)i * 128 + 1);
    }
    floatx4 acc0 = {0.f, 0.f, 0.f, 0.f}, acc1 = acc0, acc2 = acc0, acc3 = acc0;
#pragma unroll
    for (int i = 0; i < 8; ++i) {
      acc0 = __builtin_amdgcn_mfma_f32_16x16x32_bf16(a[i].v, Breg[0][i].v, acc0, 0, 0, 0);
      acc1 = __builtin_amdgcn_mfma_f32_16x16x32_bf16(a[i].v, Breg[1][i].v, acc1, 0, 0, 0);
      acc2 = __builtin_amdgcn_mfma_f32_16x16x32_bf16(a[i].v, Breg[2][i].v, acc2, 0, 0, 0);
      acc3 = __builtin_amdgcn_mfma_f32_16x16x32_bf16(a[i].v, Breg[3][i].v, acc3, 0, 0, 0);
    }
    par ^= 1;
    return reduce4(acc0, acc1, acc2, acc3);
  };

  auto block_sum = [&](float v) -> float {
#pragma unroll
    for (int o = 32; o; o >>= 1) v += __shfl_down(v, o, 64);
    __syncthreads();
    if (lane == 0) bred[w] = v;
    __syncthreads();
    return (tid == 0) ? (bred[0] + bred[1] + bred[2] + bred[3]) : 0.0f;
  };

  // single-level deterministic grid reduce: every block posts partial+flag,
  // wave 0 polls all 256 flags (4/lane) then sums all 256 partials locally
  // in a fixed lane/shuffle order (identical in every block).
  auto grid_reduce = [&](float va, float vb, int sa, int sb, bool two) -> float2 {
    float ba = block_sum(va);
    float bb = two ? block_sum(vb) : 0.0f;
    ++rg_phase;
    if (tid == 0) {
      AST(&PART1[sa * 256 + blk], ba);
      if (two) AST(&PART1[sb * 256 + blk], bb);
      asm volatile("s_waitcnt vmcnt(0)" ::: "memory");
      AST(&FLAG[blk * 8], (unsigned)rg_phase);
    }
    if (w == 0) {
#pragma unroll
      for (int k = 0; k < 4; ++k) {
        while (ALD(&FLAG[(lane + 64 * k) * 8]) < (unsigned)rg_phase)
          __builtin_amdgcn_s_sleep(1);
      }
      float x0 = ALD(&PART1[sa * 256 + lane]) + ALD(&PART1[sa * 256 + lane + 64]) +
                 ALD(&PART1[sa * 256 + lane + 128]) + ALD(&PART1[sa * 256 + lane + 192]);
      float x1 = 0.0f;
      if (two)
        x1 = ALD(&PART1[sb * 256 + lane]) + ALD(&PART1[sb * 256 + lane + 64]) +
             ALD(&PART1[sb * 256 + lane + 128]) + ALD(&PART1[sb * 256 + lane + 192]);
#pragma unroll
      for (int o = 32; o; o >>= 1) {
        x0 += __shfl_down(x0, o, 64);
        x1 += __shfl_down(x1, o, 64);
      }
      if (lane == 0) { shb0s = x0; shb1s = x1; }
    }
    __syncthreads();
    return make_float2(shb0s, shb1s);
  };

  // ---- phase A0: y = (x @ P) patch, K=512 MFMA vs pre-packed P-frags ----
  floatx4 y, fy, k2, k3, k4, k5, k6, k7, yn, av;
  {
    for (int idx = tid; idx < 8192; idx += 256) {
      int r = idx >> 9, k = idx & 511;
      float v = x[(size_t)(rg * 16 + r) * NDT + k];
      int al = r | (((k >> 3) & 3) << 4);
      ldsX[((size_t)(k >> 5) * 64 + al) * 8 + (k & 7)] = (unsigned short)f2bf(v);
    }
    __syncthreads();
    floatx4 a0 = {0.f, 0.f, 0.f, 0.f}, a1 = a0, a2 = a0, a3 = a0;
#pragma unroll
    for (int i = 0; i < 4; ++i) {
      UB a, b;
      a.u = *(const uint4*)(ldsX + ((size_t)(4 * w + i) * 64 + lane) * 8);
      b.u = *(const uint4*)(BfP + (((size_t)(cb * 4 + 0) * 16 + 4 * w + i) * 64 + lane) * 8);
      a0 = __builtin_amdgcn_mfma_f32_16x16x32_bf16(a.v, b.v, a0, 0, 0, 0);
      b.u = *(const uint4*)(BfP + (((size_t)(cb * 4 + 1) * 16 + 4 * w + i) * 64 + lane) * 8);
      a1 = __builtin_amdgcn_mfma_f32_16x16x32_bf16(a.v, b.v, a1, 0, 0, 0);
      b.u = *(const uint4*)(BfP + (((size_t)(cb * 4 + 2) * 16 + 4 * w + i) * 64 + lane) * 8);
      a2 = __builtin_amdgcn_mfma_f32_16x16x32_bf16(a.v, b.v, a2, 0, 0, 0);
      b.u = *(const uint4*)(BfP + (((size_t)(cb * 4 + 3) * 16 + 4 * w + i) * 64 + lane) * 8);
      a3 = __builtin_amdgcn_mfma_f32_16x16x32_bf16(a.v, b.v, a3, 0, 0, 0);
    }
    y = reduce4(a0, a1, a2, a3);
  }

  // ---- initial step selection (scipy _select_initial_step) ----
  write_basis(y, TCc + TBc * 0.0f);
  rg_barrier();
  fy = gemm();  // f0
  {
    float s0 = 0.f, s1 = 0.f;
#pragma unroll
    for (int r = 0; r < 4; ++r) {
      float sv = ATOLc + RTOLc * fabsf(y[r]);
      float a = y[r] / sv, b = fy[r] / sv;
      s0 += a * a;
      s1 += b * b;
    }
    float2 d01 = grid_reduce(s0, s1, 0, 1, true);
    const float d0 = sqrtf(d01.x / NELF);
    const float d1 = sqrtf(d01.y / NELF);
    const float h0 = (d0 < 1e-5f || d1 < 1e-5f) ? 1e-6f : 0.01f * d0 / d1;
    av = y + h0 * fy;
    write_basis(av, TCc + TBc * h0);
    rg_barrier();
    k2 = gemm();  // f1 (temp)
    float s2 = 0.f;
#pragma unroll
    for (int r = 0; r < 4; ++r) {
      float sv = ATOLc + RTOLc * fabsf(y[r]);
      float dd = (k2[r] - fy[r]) / sv;
      s2 += dd * dd;
    }
    const float d2 = sqrtf(grid_reduce(s2, 0.f, 2, 0, false).x / NELF) / h0;
    const float dmax = fmaxf(d1, d2);
    const float h1i = (dmax <= 1e-15f) ? fmaxf(1e-6f, h0 * 1e-3f) : powf(0.01f / dmax, 0.2f);
    float h = fminf(fminf(100.0f * h0, h1i), 1.0f);
    float t = 0.0f;
    bool done = false;
    int it = 0;

    const float a21 = (float)(1.0 / 5.0);
    const float a31 = (float)(3.0 / 40.0), a32 = (float)(9.0 / 40.0);
    const float a41 = (float)(44.0 / 45.0), a42 = (float)(-56.0 / 15.0), a43 = (float)(32.0 / 9.0);
    const float a51 = (float)(19372.0 / 6561.0), a52 = (float)(-25360.0 / 2187.0),
                a53 = (float)(64448.0 / 6561.0), a54 = (float)(-212.0 / 729.0);
    const float a61 = (float)(9017.0 / 3168.0), a62 = (float)(-355.0 / 33.0),
                a63 = (float)(46732.0 / 5247.0), a64 = (float)(49.0 / 176.0),
                a65 = (float)(-5103.0 / 18656.0);
    const float b1 = (float)(35.0 / 384.0), b3 = (float)(500.0 / 1113.0),
                b4 = (float)(125.0 / 192.0), b5 = (float)(-2187.0 / 6784.0),
                b6 = (float)(11.0 / 84.0);
    const float e1c = (float)(71.0 / 57600.0), e3c = (float)(-71.0 / 16695.0),
                e4c = (float)(71.0 / 1920.0), e5c = (float)(-17253.0 / 339200.0),
                e6c = (float)(22.0 / 525.0), e7c = (float)(-1.0 / 40.0);
    const float c89 = (float)(8.0 / 9.0);

    while (true) {
      const float hs = fminf(h, 1.0f - t);

      av = y + (hs * a21) * fy;
      write_basis(av, TCc + TBc * (t + 0.2f * hs));
      rg_barrier();
      k2 = gemm();

      av = y + hs * (a31 * fy + a32 * k2);
      write_basis(av, TCc + TBc * (t + 0.3f * hs));
      rg_barrier();
      k3 = gemm();

      av = y + hs * (a41 * fy + a42 * k2 + a43 * k3);
      write_basis(av, TCc + TBc * (t + 0.8f * hs));
      rg_barrier();
      k4 = gemm();

      av = y + hs * (a51 * fy + a52 * k2 + a53 * k3 + a54 * k4);
      write_basis(av, TCc + TBc * (t + c89 * hs));
      rg_barrier();
      k5 = gemm();

      av = y + hs * (a61 * fy + a62 * k2 + a63 * k3 + a64 * k4 + a65 * k5);
      write_basis(av, TCc + TBc * (t + hs));
      rg_barrier();
      k6 = gemm();

      yn = y + hs * (b1 * fy + b3 * k3 + b4 * k4 + b5 * k5 + b6 * k6);
      write_basis(yn, TCc + TBc * (t + hs));  // FSAL stage input
      rg_barrier();
      k7 = gemm();

      float es = 0.f;
#pragma unroll
      for (int r = 0; r < 4; ++r) {
        float errc = hs * (e1c * fy[r] + e3c * k3[r] + e4c * k4[r] + e5c * k5[r] + e6c * k6[r] +
                           e7c * k7[r]);
        float sv = ATOLc + RTOLc * fmaxf(fabsf(y[r]), fabsf(yn[r]));
        float dd = errc / sv;
        es += dd * dd;
      }
      const float en = sqrtf(grid_reduce(es, 0.f, 3 + it, 0, false).x / NELF);
      const bool accept = en < 1.0f;
      const float safe = fmaxf(en, 1e-10f);
      float fac = 0.9f * powf(safe, -0.2f);
      fac = accept ? fminf(10.0f, fac) : fmaxf(0.2f, fac);
      if (accept) {
        t = t + hs;
        y = yn;
        fy = k7;
      }
      h = hs * fac;
      done = done || (t >= 1.0f - 1e-7f);
      ++it;
      if (done || it >= 20) break;
    }
  }

  // ---- final phase: out = A_f @ F. Exchange y as K=512 frags in the AF0
  // region (safe: last grid_reduce was a full grid sync; no more basis gemms).
  {
    uint32_t d0 = f2bf(y[0]) | (f2bf(y[1]) << 16);
    uint32_t d1 = f2bf(y[2]) | (f2bf(y[3]) << 16);
    const int kcF = gcq >> 3;
    const int alF = rl | (((gcq >> 1) & 3) << 4);
    AST(YF + ((size_t)(rg * 16 + kcF) * 64 + alF) * 2 + (gcq & 1),
        (unsigned long long)d0 | ((unsigned long long)d1 << 32));
  }
  rg_barrier();
  {
    floatx4 a0 = {0.f, 0.f, 0.f, 0.f}, a1 = a0, a2 = a0, a3 = a0;
#pragma unroll
    for (int i = 0; i < 4; ++i) {
      UB2 a;
      const size_t base = ((size_t)(rg * 16 + 4 * w + i) * 64 + lane) * 2;
      a.q[0] = ALD(YF + base);
      a.q[1] = ALD(YF + base + 1);
      UB b;
      b.u = *(const uint4*)(BfF + (((size_t)(cb * 4 + 0) * 16 + 4 * w + i) * 64 + lane) * 8);
      a0 = __builtin_amdgcn_mfma_f32_16x16x32_bf16(a.v, b.v, a0, 0, 0, 0);
      b.u = *(const uint4*)(BfF + (((size_t)(cb * 4 + 1) * 16 + 4 * w + i) * 64 + lane) * 8);
      a1 = __builtin_amdgcn_mfma_f32_16x16x32_bf16(a.v, b.v, a1, 0, 0, 0);
      b.u = *(const uint4*)(BfF + (((size_t)(cb * 4 + 2) * 16 + 4 * w + i) * 64 + lane) * 8);
      a2 = __builtin_amdgcn_mfma_f32_16x16x32_bf16(a.v, b.v, a2, 0, 0, 0);
      b.u = *(const uint4*)(BfF + (((size_t)(cb * 4 + 3) * 16 + 4 * w + i) * 64 + lane) * 8);
      a3 = __builtin_amdgcn_mfma_f32_16x16x32_bf16(a.v, b.v, a3, 0, 0, 0);
    }
    floatx4 o = reduce4(a0, a1, a2, a3);
    *(floatx4*)(out + (size_t)(rg * 16 + rl) * NDT + cb * 64 + (tid >> 4) * 4) = o;
  }
}

extern "C" void kernel_launch(void* const* d_in, const int* in_sizes, int n_in,
                              void* d_out, int out_size, void* d_ws, size_t ws_size,
                              hipStream_t stream) {
  (void)in_sizes; (void)n_in; (void)out_size; (void)ws_size;
  const float* x = (const float*)d_in[0];
  const float* P = (const float*)d_in[1];
  const float* C = (const float*)d_in[2];
  const float* F = (const float*)d_in[3];
  float* out = (float*)d_out;
  float* ws = (float*)d_ws;

  // pack C/P/F -> bf16 frags, zero ctl region (block 0)
  hipLaunchKernelGGL(pack_all, dim3(768), dim3(256), 0, stream, C, P, F,
                     (__bf16*)(ws + BFC_OFF), (unsigned*)(ws + BFP_OFF),
                     (unsigned*)(ws + BFF_OFF), (unsigned*)ws);
  // fused kernel: A0 + RK45 + out (plain launch, flag barriers, 1-level reduce)
  hipLaunchKernelGGL(ode_mfma, dim3(256), dim3(256), 0, stream, x, out, ws);
}